// Round 2
// baseline (11285.950 us; speedup 1.0000x reference)
//
#include <hip/hip_runtime.h>
#include <hip/hip_bf16.h>
#include <math.h>

// Problem constants
#define BB 4
#define MM 20
#define LL 200
#define INC 2048
#define C1 512
#define C2 256
#define CDIM 300
#define DC1 512
#define DC2 256
#define SDIM 1024
#define BM 80           // B*M
#define L2 100          // L/2
#define L4 50           // L/4

// ---------------- weight transposes ----------------
// conv weight [co][ci][t] -> [co][t][ci]
__global__ void k_conv_w_t(const float* __restrict__ in, float* __restrict__ out,
                           int Cout, int Cin, int Kk) {
  int idx = blockIdx.x * 256 + threadIdx.x;
  int total = Cout * Cin * Kk;
  if (idx >= total) return;
  int ci = idx % Cin;
  int t  = (idx / Cin) % Kk;
  int co = idx / (Cin * Kk);
  out[idx] = in[(co * Cin + ci) * Kk + t];
}

// deconv weight [ci][co][t] -> [t][co][ci]
__global__ void k_deconv_w_t(const float* __restrict__ in, float* __restrict__ out,
                             int Cin, int Cout, int Kk) {
  int idx = blockIdx.x * 256 + threadIdx.x;
  int total = Cin * Cout * Kk;
  if (idx >= total) return;
  int ci = idx % Cin;
  int co = (idx / Cin) % Cout;
  int t  = idx / (Cin * Cout);
  out[idx] = in[(ci * Cout + co) * Kk + t];
}

// ---------------- small precompute: q[z][b][c], v[z][b][c] ----------------
__global__ __launch_bounds__(256) void k_prep_small(
    const float* __restrict__ concept1, const float* __restrict__ concept2,
    const float* __restrict__ w_ca1, const float* __restrict__ w_sim1,
    const float* __restrict__ w_sim2, const float* __restrict__ w_mlp,
    float* __restrict__ qv) {
  int cz = blockIdx.x >> 2;
  int b  = blockIdx.x & 3;
  const float* con = cz ? concept2 : concept1;
  __shared__ float cvec[CDIM];
  __shared__ float chat[SDIM];
  int tid = threadIdx.x;
  for (int j = tid; j < CDIM; j += 256) cvec[j] = con[b * CDIM + j];
  __syncthreads();
  // q[tid] = concept . w_ca1[tid,:]
  float accq = 0.f;
  for (int j = 0; j < CDIM; ++j) accq += cvec[j] * w_ca1[tid * CDIM + j];
  qv[(cz * 4 + b) * 256 + tid] = accq;
  // chat[s] = (concept . w_sim2[s,:]) * w_mlp[s]
  for (int i = 0; i < 4; ++i) {
    int s = tid + i * 256;
    float a2 = 0.f;
    for (int j = 0; j < CDIM; ++j) a2 += cvec[j] * w_sim2[s * CDIM + j];
    chat[s] = a2 * w_mlp[s];
  }
  __syncthreads();
  // v[tid] = sum_s w_sim1[s][tid] * chat[s]
  float v = 0.f;
  for (int s = 0; s < SDIM; ++s) v += w_sim1[s * 256 + tid] * chat[s];
  qv[2048 + (cz * 4 + b) * 256 + tid] = v;
}

// ---------------- conv(k=5,pad=2) as GEMM + fused maxpool2 + bias ----------------
// X: [z][Lin][Cin], W: [Ncols][5*Cin], Out: [z][Lin/2][Ncols]
__global__ __launch_bounds__(256) void k_conv_pool_gemm(
    const float* __restrict__ X, const float* __restrict__ W,
    const float* __restrict__ bias, float* __restrict__ Out,
    int Lin, int Cin, int Ncols) {
  __shared__ __align__(16) float As[64][68];
  __shared__ __align__(16) float Bs[128][68];
  int n = blockIdx.z;
  int l0 = blockIdx.y * 64;
  int col0 = blockIdx.x * 128;
  int tid = threadIdx.x;
  int ty = tid >> 4, tx = tid & 15;
  float acc[4][8] = {};
  int K = 5 * Cin;
  int cpt = Cin >> 6;  // 64-float k-chunks per tap
  const float* Xn = X + (long long)n * Lin * Cin;
  for (int c = 0; c < 5 * cpt; ++c) {
    int t = c / cpt;
    int ci0 = (c % cpt) << 6;
    #pragma unroll
    for (int i = 0; i < 4; ++i) {
      int idx = tid + i * 256; int r = idx >> 4, q = idx & 15;
      int j = l0 + r + t - 2;
      float4 v = make_float4(0.f, 0.f, 0.f, 0.f);
      if (j >= 0 && j < Lin) v = *(const float4*)&Xn[(long long)j * Cin + ci0 + q * 4];
      *(float4*)&As[r][q * 4] = v;
    }
    #pragma unroll
    for (int i = 0; i < 8; ++i) {
      int idx = tid + i * 256; int r = idx >> 4, q = idx & 15;
      *(float4*)&Bs[r][q * 4] =
          *(const float4*)&W[(long long)(col0 + r) * K + t * Cin + ci0 + q * 4];
    }
    __syncthreads();
    #pragma unroll
    for (int k4 = 0; k4 < 64; k4 += 4) {
      float4 av[4]; float4 bv[8];
      #pragma unroll
      for (int i = 0; i < 4; ++i) av[i] = *(const float4*)&As[ty * 4 + i][k4];
      #pragma unroll
      for (int jj = 0; jj < 8; ++jj) bv[jj] = *(const float4*)&Bs[tx + 16 * jj][k4];
      #pragma unroll
      for (int i = 0; i < 4; ++i)
        #pragma unroll
        for (int jj = 0; jj < 8; ++jj)
          acc[i][jj] += av[i].x * bv[jj].x + av[i].y * bv[jj].y +
                        av[i].z * bv[jj].z + av[i].w * bv[jj].w;
    }
    __syncthreads();
  }
  // fused maxpool2 + bias: thread rows l0+ty*4+{0..3} = pool pairs -> lo, lo+1
  int Lout = Lin >> 1;
  #pragma unroll
  for (int p = 0; p < 2; ++p) {
    int lo = (l0 >> 1) + ty * 2 + p;
    if (lo < Lout) {
      #pragma unroll
      for (int jj = 0; jj < 8; ++jj) {
        int col = col0 + tx + 16 * jj;
        Out[((long long)n * Lout + lo) * Ncols + col] =
            fmaxf(acc[2 * p][jj], acc[2 * p + 1][jj]) + bias[col];
      }
    }
  }
}

// ---------------- generic fp32 GEMM: C[M][N] = A[M][K] * B[N][K]^T, batched over z ----------------
__global__ __launch_bounds__(256) void k_gemm_nt(
    const float* __restrict__ A, const float* __restrict__ B, float* __restrict__ C,
    int M, int N, int K, long long sB, long long sC) {
  __shared__ __align__(16) float As[64][68];
  __shared__ __align__(16) float Bs[128][68];
  int tap = blockIdx.z;
  const float* Bp = B + (long long)tap * sB;
  float* Cp = C + (long long)tap * sC;
  int row0 = blockIdx.y * 64;
  int col0 = blockIdx.x * 128;
  int tid = threadIdx.x;
  int ty = tid >> 4, tx = tid & 15;
  float acc[4][8] = {};
  for (int kc = 0; kc < K; kc += 64) {
    #pragma unroll
    for (int i = 0; i < 4; ++i) {
      int idx = tid + i * 256; int r = idx >> 4, q = idx & 15;
      int gr = row0 + r;
      float4 v = make_float4(0.f, 0.f, 0.f, 0.f);
      if (gr < M) v = *(const float4*)&A[(long long)gr * K + kc + q * 4];
      *(float4*)&As[r][q * 4] = v;
    }
    #pragma unroll
    for (int i = 0; i < 8; ++i) {
      int idx = tid + i * 256; int r = idx >> 4, q = idx & 15;
      *(float4*)&Bs[r][q * 4] = *(const float4*)&Bp[(long long)(col0 + r) * K + kc + q * 4];
    }
    __syncthreads();
    #pragma unroll
    for (int k4 = 0; k4 < 64; k4 += 4) {
      float4 av[4]; float4 bv[8];
      #pragma unroll
      for (int i = 0; i < 4; ++i) av[i] = *(const float4*)&As[ty * 4 + i][k4];
      #pragma unroll
      for (int jj = 0; jj < 8; ++jj) bv[jj] = *(const float4*)&Bs[tx + 16 * jj][k4];
      #pragma unroll
      for (int i = 0; i < 4; ++i)
        #pragma unroll
        for (int jj = 0; jj < 8; ++jj)
          acc[i][jj] += av[i].x * bv[jj].x + av[i].y * bv[jj].y +
                        av[i].z * bv[jj].z + av[i].w * bv[jj].w;
    }
    __syncthreads();
  }
  for (int i = 0; i < 4; ++i) {
    int gr = row0 + ty * 4 + i;
    if (gr < M) {
      #pragma unroll
      for (int jj = 0; jj < 8; ++jj)
        Cp[(long long)gr * N + col0 + tx + 16 * jj] = acc[i][jj];
    }
  }
}

// ---------------- attention: scores + masked softmax + weighted sum ----------------
__global__ __launch_bounds__(256) void k_attention(
    const float* __restrict__ kproj, const float* __restrict__ t2,
    const float* __restrict__ qv, const float* __restrict__ w_ca3,
    const int* __restrict__ seg_len, float* __restrict__ r_out) {
  int bidx = blockIdx.x;
  int bm = bidx % BM;
  int cz = bidx / BM;
  int b = bm / MM;
  int tid = threadIdx.x;
  float q = qv[(cz * 4 + b) * 256 + tid];
  float w3 = w_ca3[tid];
  int seg = seg_len[bm];
  int kmax = (seg + 3) >> 2;
  __shared__ float sred[4];
  __shared__ float sa[L4];
  for (int k = 0; k < L4; ++k) {
    float val = tanhf(q + kproj[(bm * L4 + k) * 256 + tid]) * w3;
    for (int off = 32; off > 0; off >>= 1) val += __shfl_down(val, off, 64);
    if ((tid & 63) == 0) sred[tid >> 6] = val;
    __syncthreads();
    if (tid == 0) {
      float s = sred[0] + sred[1] + sred[2] + sred[3];
      sa[k] = (k < kmax) ? s : -1e15f;
    }
    __syncthreads();
  }
  if (tid == 0) {
    float mx = -3e38f;
    for (int k = 0; k < L4; ++k) mx = fmaxf(mx, sa[k]);
    float sum = 0.f;
    for (int k = 0; k < L4; ++k) { float e = expf(sa[k] - mx); sa[k] = e; sum += e; }
    float inv = 1.f / sum;
    for (int k = 0; k < L4; ++k) sa[k] *= inv;
  }
  __syncthreads();
  float r = 0.f;
  for (int k = 0; k < L4; ++k) r += sa[k] * t2[(bm * L4 + k) * 256 + tid];
  r_out[(cz * BM + bm) * 256 + tid] = r;
}

// ---------------- build cat matrix [4000][768] ----------------
__global__ void k_build_cat(const float* __restrict__ t2, const float* __restrict__ r_out,
                            float* __restrict__ catm, int total) {
  int idx = blockIdx.x * 256 + threadIdx.x;
  if (idx >= total) return;
  int ci = idx % 768;
  int row = idx / 768;        // bm*50 + li
  int bm = row / L4;
  float v;
  if (ci < 256)      v = t2[row * 256 + ci];
  else if (ci < 512) v = r_out[bm * 256 + (ci - 256)];
  else               v = r_out[(BM + bm) * 256 + (ci - 512)];
  catm[idx] = v;
}

// ---------------- deconv1 combine (2 taps + bias) -> d1 [80][100][512] ----------------
__global__ void k_combine1(const float* __restrict__ D1tap, const float* __restrict__ b_dc1,
                           float* __restrict__ d1, int total) {
  int idx = blockIdx.x * 256 + threadIdx.x;
  if (idx >= total) return;
  int co = idx & 511;
  int lo = (idx >> 9) % L2;
  int n = idx / (512 * L2);
  int liA, tA, liB, tB;
  if (lo & 1) { tA = 2; liA = (lo - 1) >> 1; tB = 0; liB = (lo + 1) >> 1; }
  else        { tA = 3; liA = (lo >> 1) - 1; tB = 1; liB = lo >> 1; }
  float v = b_dc1[co];
  if (liA >= 0 && liA < L4) v += D1tap[((long long)tA * 4000 + n * L4 + liA) * 512 + co];
  if (liB >= 0 && liB < L4) v += D1tap[((long long)tB * 4000 + n * L4 + liB) * 512 + co];
  d1[idx] = v;
}

// ---------------- deconv2 combine + final projection + sigmoid ----------------
__global__ __launch_bounds__(256) void k_final(
    const float* __restrict__ D2tap, const float* __restrict__ b_dc2,
    const float* __restrict__ qv, const float* __restrict__ b_mlp,
    float* __restrict__ out) {
  int blk = blockIdx.x;          // n*200 + lo
  int n = blk / LL, lo = blk % LL;
  int b = n / MM, m = n % MM;
  int tid = threadIdx.x;
  int liA, tA, liB, tB;
  if (lo & 1) { tA = 2; liA = (lo - 1) >> 1; tB = 0; liB = (lo + 1) >> 1; }
  else        { tA = 3; liA = (lo >> 1) - 1; tB = 1; liB = lo >> 1; }
  float v = b_dc2[tid];
  if (liA >= 0 && liA < L2) v += D2tap[((long long)tA * 8000 + n * L2 + liA) * 256 + tid];
  if (liB >= 0 && liB < L2) v += D2tap[((long long)tB * 8000 + n * L2 + liB) * 256 + tid];
  float p1 = v * qv[2048 + (0 * 4 + b) * 256 + tid];
  float p2 = v * qv[2048 + (1 * 4 + b) * 256 + tid];
  for (int off = 32; off > 0; off >>= 1) {
    p1 += __shfl_down(p1, off, 64);
    p2 += __shfl_down(p2, off, 64);
  }
  __shared__ float s1[4], s2[4];
  if ((tid & 63) == 0) { s1[tid >> 6] = p1; s2[tid >> 6] = p2; }
  __syncthreads();
  if (tid == 0) {
    float bmlp = b_mlp[0];
    float a1 = s1[0] + s1[1] + s1[2] + s1[3] + bmlp;
    float a2 = s2[0] + s2[1] + s2[2] + s2[3] + bmlp;
    int t_idx = m * LL + lo;
    out[b * 4000 + t_idx]         = 1.f / (1.f + expf(-a1));
    out[16000 + b * 4000 + t_idx] = 1.f / (1.f + expf(-a2));
  }
}

// ---------------- host ----------------
extern "C" void kernel_launch(void* const* d_in, const int* in_sizes, int n_in,
                              void* d_out, int out_size, void* d_ws, size_t ws_size,
                              hipStream_t stream) {
  const float* batch    = (const float*)d_in[0];
  const int*   seg_len  = (const int*)d_in[1];
  const float* concept1 = (const float*)d_in[2];
  const float* concept2 = (const float*)d_in[3];
  const float* w_conv1  = (const float*)d_in[4];
  const float* b_conv1  = (const float*)d_in[5];
  const float* w_conv2  = (const float*)d_in[6];
  const float* b_conv2  = (const float*)d_in[7];
  const float* w_ca1    = (const float*)d_in[8];
  const float* w_ca2    = (const float*)d_in[9];
  const float* w_ca3    = (const float*)d_in[10];
  const float* w_dc1    = (const float*)d_in[11];
  const float* b_dc1    = (const float*)d_in[12];
  const float* w_dc2    = (const float*)d_in[13];
  const float* b_dc2    = (const float*)d_in[14];
  const float* w_sim1   = (const float*)d_in[15];
  const float* w_sim2   = (const float*)d_in[16];
  const float* w_mlp    = (const float*)d_in[17];
  const float* b_mlp    = (const float*)d_in[18];
  float* out = (float*)d_out;

  float* ws = (float*)d_ws;
  // workspace layout (floats), aliased regions — total 22,376,448 f = 85.4 MB
  const long long off_qv    = 0;           //     4,096
  const long long off_r     = 4096;        //    40,960
  const long long off_t2    = 45056;       // 1,024,000
  const long long off_kproj = 1069056;     // 1,024,000
  const long long off_wt2   = 2093056;     //   655,360
  const long long off_wdt1  = 2748416;     // 1,572,864
  const long long off_wdt2  = 4321280;     //   524,288
  const long long off_W     = 4845568;     // 5,242,880  (wt1 -> catm)
  const long long off_X     = 10088448;    // 8,192,000  (D1tap -> D2tap)
  const long long off_Y     = 18280448;    // 4,096,000  (t1 -> d1)

  // --- weight prep ---
  k_conv_w_t<<<dim3(20480), 256, 0, stream>>>(w_conv1, ws + off_W, C1, INC, 5);
  k_conv_w_t<<<dim3(2560), 256, 0, stream>>>(w_conv2, ws + off_wt2, C2, C1, 5);
  k_deconv_w_t<<<dim3(6144), 256, 0, stream>>>(w_dc1, ws + off_wdt1, 3 * C2, DC1, 4);
  k_deconv_w_t<<<dim3(2048), 256, 0, stream>>>(w_dc2, ws + off_wdt2, DC1, DC2, 4);
  k_prep_small<<<dim3(8), 256, 0, stream>>>(concept1, concept2, w_ca1, w_sim1, w_sim2,
                                            w_mlp, ws + off_qv);

  // --- conv1 + pool + bias -> t1 [80][100][512]
  k_conv_pool_gemm<<<dim3(4, 4, BM), 256, 0, stream>>>(batch, ws + off_W, b_conv1,
                                                       ws + off_Y, LL, INC, C1);
  // --- conv2 + pool + bias -> t2 [80][50][256]
  k_conv_pool_gemm<<<dim3(2, 2, BM), 256, 0, stream>>>(ws + off_Y, ws + off_wt2, b_conv2,
                                                       ws + off_t2, L2, C1, C2);

  // --- kproj = t2 @ w_ca2^T : [4000][256]  (w_ca2 used directly, fp32)
  k_gemm_nt<<<dim3(2, 63, 1), 256, 0, stream>>>(ws + off_t2, w_ca2, ws + off_kproj,
                                                4000, 256, 256, 0, 0);

  // --- attention (2 concepts x 80 rows) -> r [2][80][256]
  k_attention<<<dim3(160), 256, 0, stream>>>(ws + off_kproj, ws + off_t2, ws + off_qv,
                                             w_ca3, seg_len, ws + off_r);

  // --- cat [4000][768] (into W region; wt1 dead)
  k_build_cat<<<dim3(12000), 256, 0, stream>>>(ws + off_t2, ws + off_r, ws + off_W,
                                               4000 * 768);

  // --- deconv1 per-tap GEMMs -> D1tap [4][4000][512] (X); combine -> d1 [80][100][512] (Y)
  k_gemm_nt<<<dim3(4, 63, 4), 256, 0, stream>>>(ws + off_W, ws + off_wdt1, ws + off_X,
                                                4000, 512, 768, 512LL * 768, 4000LL * 512);
  k_combine1<<<dim3(16000), 256, 0, stream>>>(ws + off_X, b_dc1, ws + off_Y,
                                              BM * L2 * DC1);

  // --- deconv2 per-tap GEMMs -> D2tap [4][8000][256] (X; D1tap dead)
  k_gemm_nt<<<dim3(2, 125, 4), 256, 0, stream>>>(ws + off_Y, ws + off_wdt2, ws + off_X,
                                                 8000, 256, 512, 256LL * 512, 8000LL * 256);

  // --- combine + final dot + sigmoid -> out (sc1 | sc2), fp32
  k_final<<<dim3(16000), 256, 0, stream>>>(ws + off_X, b_dc2, ws + off_qv, b_mlp, out);
}

// Round 3
// 1227.235 us; speedup vs baseline: 9.1962x; 9.1962x over previous
//
#include <hip/hip_runtime.h>
#include <hip/hip_bf16.h>
#include <math.h>

// Problem constants
#define BB 4
#define MM 20
#define LL 200
#define INC 2048
#define C1 512
#define C2 256
#define CDIM 300
#define DC1 512
#define DC2 256
#define SDIM 1024
#define BM 80           // B*M
#define L2 100          // L/2
#define L4 50           // L/4

typedef unsigned short u16;
typedef __attribute__((ext_vector_type(8))) short bf16x8;
typedef __attribute__((ext_vector_type(4))) float f32x4;

__device__ __forceinline__ u16 f2bf_rne(float f) {
  unsigned u = __float_as_uint(f);
  unsigned r = u + 0x7FFFu + ((u >> 16) & 1u);
  return (u16)(r >> 16);
}

// ---------------- weight transposes (emit bf16) ----------------
// conv weight [co][ci][t] -> [co][t][ci]  (= B[N][K], K = 5*Cin)
__global__ void k_conv_w_t(const float* __restrict__ in, u16* __restrict__ out,
                           int Cout, int Cin, int Kk) {
  int idx = blockIdx.x * 256 + threadIdx.x;
  int total = Cout * Cin * Kk;
  if (idx >= total) return;
  int ci = idx % Cin;
  int t  = (idx / Cin) % Kk;
  int co = idx / (Cin * Kk);
  out[idx] = f2bf_rne(in[(co * Cin + ci) * Kk + t]);
}

// deconv weight [ci][co][t] -> [t][co][ci]
__global__ void k_deconv_w_t(const float* __restrict__ in, u16* __restrict__ out,
                             int Cin, int Cout, int Kk) {
  int idx = blockIdx.x * 256 + threadIdx.x;
  int total = Cin * Cout * Kk;
  if (idx >= total) return;
  int ci = idx % Cin;
  int co = (idx / Cin) % Cout;
  int t  = idx / (Cin * Cout);
  out[idx] = f2bf_rne(in[(ci * Cout + co) * Kk + t]);
}

// ---------------- small precompute: q[z][b][c], v[z][b][c] ----------------
__global__ __launch_bounds__(256) void k_prep_small(
    const float* __restrict__ concept1, const float* __restrict__ concept2,
    const float* __restrict__ w_ca1, const float* __restrict__ w_sim1,
    const float* __restrict__ w_sim2, const float* __restrict__ w_mlp,
    float* __restrict__ qv) {
  int cz = blockIdx.x >> 2;
  int b  = blockIdx.x & 3;
  const float* con = cz ? concept2 : concept1;
  __shared__ float cvec[CDIM];
  __shared__ float chat[SDIM];
  int tid = threadIdx.x;
  for (int j = tid; j < CDIM; j += 256) cvec[j] = con[b * CDIM + j];
  __syncthreads();
  float accq = 0.f;
  for (int j = 0; j < CDIM; ++j) accq += cvec[j] * w_ca1[tid * CDIM + j];
  qv[(cz * 4 + b) * 256 + tid] = accq;
  for (int i = 0; i < 4; ++i) {
    int s = tid + i * 256;
    float a2 = 0.f;
    for (int j = 0; j < CDIM; ++j) a2 += cvec[j] * w_sim2[s * CDIM + j];
    chat[s] = a2 * w_mlp[s];
  }
  __syncthreads();
  float v = 0.f;
  for (int s = 0; s < SDIM; ++s) v += w_sim1[s * 256 + tid] * chat[s];
  qv[2048 + (cz * 4 + b) * 256 + tid] = v;
}

// ---------------- unified bf16-MFMA NT GEMM ----------------
// C[z][M][N] = A[M][K] * B[z][N][K]^T  (A fp32 -> bf16 truncate during staging,
// B pre-cast bf16). A row r maps to (n = r/lr, l = r%lr); element k = tap*cin+ci
// reads A[(n*lr + l+tap-pad)*cin + ci], zero if out of range (im2col conv rows).
// Direct GEMM: lr = M, cin = K, pad = 0.
// ep: 0 = plain fp32 store; 1 = maxpool2(along l)+bias, out [n][lr/2][N] fp32.
#define EP_PLAIN 0
#define EP_POOL  1
#define LDK 72   // padded LDS row stride in u16 (144 B -> 4-bank rotation)

__global__ __launch_bounds__(256) void k_mfma_gemm(
    const float* __restrict__ A, const u16* __restrict__ Bw,
    float* __restrict__ C, const float* __restrict__ bias,
    int M, int N, int K, int lr, int cin, int pad,
    long long sB, long long sC, int ep) {
  __shared__ __align__(16) u16 As[128 * LDK];
  __shared__ __align__(16) u16 Bs[128 * LDK];
  int tid = threadIdx.x;
  int w = tid >> 6, ln = tid & 63;
  int row0 = blockIdx.y * 128;
  int col0 = blockIdx.x * 128;
  const u16* Bz = Bw + (long long)blockIdx.z * sB;
  float* Cz = C + (long long)blockIdx.z * sC;

  // staging: thread covers rows i*32 + (tid>>3), cols (tid&7)*8, i = 0..3
  int sub = (tid & 7) * 8;
  int rrb = tid >> 3;
  int an[4], al[4];
  #pragma unroll
  for (int i = 0; i < 4; ++i) {
    int r = row0 + i * 32 + rrb;
    if (r > M - 1) r = M - 1;
    an[i] = r / lr;
    al[i] = r - an[i] * lr;
  }
  f32x4 acc[4][4];
  #pragma unroll
  for (int i = 0; i < 4; ++i)
    #pragma unroll
    for (int j = 0; j < 4; ++j) acc[i][j] = (f32x4){0.f, 0.f, 0.f, 0.f};

  int wr = (w >> 1) * 64, wc = (w & 1) * 64;

  int tap = 0, ci0 = 0;
  for (int kc = 0; kc < K; kc += 64) {
    // stage A (fp32 -> bf16 truncate, zero-fill out-of-range conv rows)
    #pragma unroll
    for (int i = 0; i < 4; ++i) {
      int j = al[i] + tap - pad;
      uint4 pk = make_uint4(0u, 0u, 0u, 0u);
      if (j >= 0 && j < lr) {
        const float* src = A + ((long long)(an[i] * lr + j) * cin + ci0 + sub);
        float4 f0 = *(const float4*)src;
        float4 f1 = *(const float4*)(src + 4);
        pk.x = (__float_as_uint(f0.x) >> 16) | (__float_as_uint(f0.y) & 0xFFFF0000u);
        pk.y = (__float_as_uint(f0.z) >> 16) | (__float_as_uint(f0.w) & 0xFFFF0000u);
        pk.z = (__float_as_uint(f1.x) >> 16) | (__float_as_uint(f1.y) & 0xFFFF0000u);
        pk.w = (__float_as_uint(f1.z) >> 16) | (__float_as_uint(f1.w) & 0xFFFF0000u);
      }
      *(uint4*)&As[(i * 32 + rrb) * LDK + sub] = pk;
    }
    // stage B (bf16 passthrough; N is always a multiple of 128)
    #pragma unroll
    for (int i = 0; i < 4; ++i) {
      int nr = col0 + i * 32 + rrb;
      *(uint4*)&Bs[(i * 32 + rrb) * LDK + sub] =
          *(const uint4*)&Bz[(long long)nr * K + kc + sub];
    }
    __syncthreads();
    #pragma unroll
    for (int ks = 0; ks < 2; ++ks) {
      bf16x8 af[4], bf[4];
      int koff = ks * 32 + (ln >> 4) * 8;
      int arow = wr + (ln & 15);
      int brow = wc + (ln & 15);
      #pragma unroll
      for (int mi = 0; mi < 4; ++mi)
        af[mi] = *(const bf16x8*)&As[(arow + mi * 16) * LDK + koff];
      #pragma unroll
      for (int ni = 0; ni < 4; ++ni)
        bf[ni] = *(const bf16x8*)&Bs[(brow + ni * 16) * LDK + koff];
      #pragma unroll
      for (int mi = 0; mi < 4; ++mi)
        #pragma unroll
        for (int ni = 0; ni < 4; ++ni)
          acc[mi][ni] = __builtin_amdgcn_mfma_f32_16x16x32_bf16(
              af[mi], bf[ni], acc[mi][ni], 0, 0, 0);
    }
    __syncthreads();
    ci0 += 64;
    if (ci0 >= cin) { ci0 = 0; ++tap; }
  }

  // epilogue: C/D layout col = lane&15, row = (lane>>4)*4 + reg
  if (ep == EP_PLAIN) {
    #pragma unroll
    for (int mi = 0; mi < 4; ++mi) {
      int gbase = row0 + wr + mi * 16 + (ln >> 4) * 4;
      #pragma unroll
      for (int r = 0; r < 4; ++r) {
        int grow = gbase + r;
        if (grow < M) {
          #pragma unroll
          for (int ni = 0; ni < 4; ++ni) {
            int col = col0 + wc + ni * 16 + (ln & 15);
            Cz[(long long)grow * N + col] = acc[mi][ni][r];
          }
        }
      }
    }
  } else {
    // maxpool2 + bias: rows (2p, 2p+1) -> out row grow/2 (lr even => same n)
    #pragma unroll
    for (int mi = 0; mi < 4; ++mi) {
      int gbase = row0 + wr + mi * 16 + (ln >> 4) * 4;
      #pragma unroll
      for (int p = 0; p < 2; ++p) {
        int grow = gbase + 2 * p;
        if (grow < M) {
          int lo = grow >> 1;
          #pragma unroll
          for (int ni = 0; ni < 4; ++ni) {
            int col = col0 + wc + ni * 16 + (ln & 15);
            float v = fmaxf(acc[mi][ni][2 * p], acc[mi][ni][2 * p + 1]) + bias[col];
            Cz[(long long)lo * N + col] = v;
          }
        }
      }
    }
  }
}

// ---------------- fp32 GEMM (kproj only): C[M][N] = A[M][K] * B[N][K]^T ----------------
__global__ __launch_bounds__(256) void k_gemm_nt(
    const float* __restrict__ A, const float* __restrict__ B, float* __restrict__ C,
    int M, int N, int K) {
  __shared__ __align__(16) float As[64][68];
  __shared__ __align__(16) float Bs[128][68];
  int row0 = blockIdx.y * 64;
  int col0 = blockIdx.x * 128;
  int tid = threadIdx.x;
  int ty = tid >> 4, tx = tid & 15;
  float acc[4][8] = {};
  for (int kc = 0; kc < K; kc += 64) {
    #pragma unroll
    for (int i = 0; i < 4; ++i) {
      int idx = tid + i * 256; int r = idx >> 4, q = idx & 15;
      int gr = row0 + r;
      float4 v = make_float4(0.f, 0.f, 0.f, 0.f);
      if (gr < M) v = *(const float4*)&A[(long long)gr * K + kc + q * 4];
      *(float4*)&As[r][q * 4] = v;
    }
    #pragma unroll
    for (int i = 0; i < 8; ++i) {
      int idx = tid + i * 256; int r = idx >> 4, q = idx & 15;
      *(float4*)&Bs[r][q * 4] = *(const float4*)&B[(long long)(col0 + r) * K + kc + q * 4];
    }
    __syncthreads();
    #pragma unroll
    for (int k4 = 0; k4 < 64; k4 += 4) {
      float4 av[4]; float4 bv[8];
      #pragma unroll
      for (int i = 0; i < 4; ++i) av[i] = *(const float4*)&As[ty * 4 + i][k4];
      #pragma unroll
      for (int jj = 0; jj < 8; ++jj) bv[jj] = *(const float4*)&Bs[tx + 16 * jj][k4];
      #pragma unroll
      for (int i = 0; i < 4; ++i)
        #pragma unroll
        for (int jj = 0; jj < 8; ++jj)
          acc[i][jj] += av[i].x * bv[jj].x + av[i].y * bv[jj].y +
                        av[i].z * bv[jj].z + av[i].w * bv[jj].w;
    }
    __syncthreads();
  }
  for (int i = 0; i < 4; ++i) {
    int gr = row0 + ty * 4 + i;
    if (gr < M) {
      #pragma unroll
      for (int jj = 0; jj < 8; ++jj)
        C[(long long)gr * N + col0 + tx + 16 * jj] = acc[i][jj];
    }
  }
}

// ---------------- attention: scores + masked softmax + weighted sum ----------------
__global__ __launch_bounds__(256) void k_attention(
    const float* __restrict__ kproj, const float* __restrict__ t2,
    const float* __restrict__ qv, const float* __restrict__ w_ca3,
    const int* __restrict__ seg_len, float* __restrict__ r_out) {
  int bidx = blockIdx.x;
  int bm = bidx % BM;
  int cz = bidx / BM;
  int b = bm / MM;
  int tid = threadIdx.x;
  float q = qv[(cz * 4 + b) * 256 + tid];
  float w3 = w_ca3[tid];
  int seg = seg_len[bm];
  int kmax = (seg + 3) >> 2;
  __shared__ float sred[4];
  __shared__ float sa[L4];
  for (int k = 0; k < L4; ++k) {
    float val = tanhf(q + kproj[(bm * L4 + k) * 256 + tid]) * w3;
    for (int off = 32; off > 0; off >>= 1) val += __shfl_down(val, off, 64);
    if ((tid & 63) == 0) sred[tid >> 6] = val;
    __syncthreads();
    if (tid == 0) {
      float s = sred[0] + sred[1] + sred[2] + sred[3];
      sa[k] = (k < kmax) ? s : -1e15f;
    }
    __syncthreads();
  }
  if (tid == 0) {
    float mx = -3e38f;
    for (int k = 0; k < L4; ++k) mx = fmaxf(mx, sa[k]);
    float sum = 0.f;
    for (int k = 0; k < L4; ++k) { float e = expf(sa[k] - mx); sa[k] = e; sum += e; }
    float inv = 1.f / sum;
    for (int k = 0; k < L4; ++k) sa[k] *= inv;
  }
  __syncthreads();
  float r = 0.f;
  for (int k = 0; k < L4; ++k) r += sa[k] * t2[(bm * L4 + k) * 256 + tid];
  r_out[(cz * BM + bm) * 256 + tid] = r;
}

// ---------------- build cat matrix [4000][768] fp32 ----------------
__global__ void k_build_cat(const float* __restrict__ t2, const float* __restrict__ r_out,
                            float* __restrict__ catm, int total) {
  int idx = blockIdx.x * 256 + threadIdx.x;
  if (idx >= total) return;
  int ci = idx % 768;
  int row = idx / 768;        // bm*50 + li
  int bm = row / L4;
  float v;
  if (ci < 256)      v = t2[row * 256 + ci];
  else if (ci < 512) v = r_out[bm * 256 + (ci - 256)];
  else               v = r_out[(BM + bm) * 256 + (ci - 512)];
  catm[idx] = v;
}

// ---------------- deconv1 combine (2 taps + bias) -> d1 [80][100][512] fp32 ----------------
__global__ void k_combine1(const float* __restrict__ D1tap, const float* __restrict__ b_dc1,
                           float* __restrict__ d1, int total) {
  int idx = blockIdx.x * 256 + threadIdx.x;
  if (idx >= total) return;
  int co = idx & 511;
  int lo = (idx >> 9) % L2;
  int n = idx / (512 * L2);
  int liA, tA, liB, tB;
  if (lo & 1) { tA = 2; liA = (lo - 1) >> 1; tB = 0; liB = (lo + 1) >> 1; }
  else        { tA = 3; liA = (lo >> 1) - 1; tB = 1; liB = lo >> 1; }
  float v = b_dc1[co];
  if (liA >= 0 && liA < L4) v += D1tap[((long long)tA * 4000 + n * L4 + liA) * 512 + co];
  if (liB >= 0 && liB < L4) v += D1tap[((long long)tB * 4000 + n * L4 + liB) * 512 + co];
  d1[idx] = v;
}

// ---------------- deconv2 combine + final projection + sigmoid ----------------
__global__ __launch_bounds__(256) void k_final(
    const float* __restrict__ D2tap, const float* __restrict__ b_dc2,
    const float* __restrict__ qv, const float* __restrict__ b_mlp,
    float* __restrict__ out) {
  int blk = blockIdx.x;          // n*200 + lo
  int n = blk / LL, lo = blk % LL;
  int b = n / MM, m = n % MM;
  int tid = threadIdx.x;
  int liA, tA, liB, tB;
  if (lo & 1) { tA = 2; liA = (lo - 1) >> 1; tB = 0; liB = (lo + 1) >> 1; }
  else        { tA = 3; liA = (lo >> 1) - 1; tB = 1; liB = lo >> 1; }
  float v = b_dc2[tid];
  if (liA >= 0 && liA < L2) v += D2tap[((long long)tA * 8000 + n * L2 + liA) * 256 + tid];
  if (liB >= 0 && liB < L2) v += D2tap[((long long)tB * 8000 + n * L2 + liB) * 256 + tid];
  float p1 = v * qv[2048 + (0 * 4 + b) * 256 + tid];
  float p2 = v * qv[2048 + (1 * 4 + b) * 256 + tid];
  for (int off = 32; off > 0; off >>= 1) {
    p1 += __shfl_down(p1, off, 64);
    p2 += __shfl_down(p2, off, 64);
  }
  __shared__ float s1[4], s2[4];
  if ((tid & 63) == 0) { s1[tid >> 6] = p1; s2[tid >> 6] = p2; }
  __syncthreads();
  if (tid == 0) {
    float bmlp = b_mlp[0];
    float a1 = s1[0] + s1[1] + s1[2] + s1[3] + bmlp;
    float a2 = s2[0] + s2[1] + s2[2] + s2[3] + bmlp;
    int t_idx = m * LL + lo;
    out[b * 4000 + t_idx]         = 1.f / (1.f + expf(-a1));
    out[16000 + b * 4000 + t_idx] = 1.f / (1.f + expf(-a2));
  }
}

// ---------------- host ----------------
extern "C" void kernel_launch(void* const* d_in, const int* in_sizes, int n_in,
                              void* d_out, int out_size, void* d_ws, size_t ws_size,
                              hipStream_t stream) {
  const float* batch    = (const float*)d_in[0];
  const int*   seg_len  = (const int*)d_in[1];
  const float* concept1 = (const float*)d_in[2];
  const float* concept2 = (const float*)d_in[3];
  const float* w_conv1  = (const float*)d_in[4];
  const float* b_conv1  = (const float*)d_in[5];
  const float* w_conv2  = (const float*)d_in[6];
  const float* b_conv2  = (const float*)d_in[7];
  const float* w_ca1    = (const float*)d_in[8];
  const float* w_ca2    = (const float*)d_in[9];
  const float* w_ca3    = (const float*)d_in[10];
  const float* w_dc1    = (const float*)d_in[11];
  const float* b_dc1    = (const float*)d_in[12];
  const float* w_dc2    = (const float*)d_in[13];
  const float* b_dc2    = (const float*)d_in[14];
  const float* w_sim1   = (const float*)d_in[15];
  const float* w_sim2   = (const float*)d_in[16];
  const float* w_mlp    = (const float*)d_in[17];
  const float* b_mlp    = (const float*)d_in[18];
  float* out = (float*)d_out;

  float* ws = (float*)d_ws;
  // workspace layout (float units), same footprint as round 2 (85.4 MB known-safe)
  const long long off_qv    = 0;           //     4,096
  const long long off_r     = 4096;        //    40,960
  const long long off_t2    = 45056;       // 1,024,000 fp32 t2
  const long long off_kproj = 1069056;     // 1,024,000
  const long long off_wt2   = 2093056;     //   655,360 (w2b bf16, half-used)
  const long long off_wdt1  = 2748416;     // 1,572,864 (wd1b bf16, half-used)
  const long long off_wdt2  = 4321280;     //   524,288 (wd2b bf16, half-used)
  const long long off_W     = 4845568;     // 5,242,880 (w1b bf16 -> catm fp32)
  const long long off_X     = 10088448;    // 8,192,000 (D1tap -> D2tap fp32)
  const long long off_Y     = 18280448;    // 4,096,000 (t1 fp32 -> d1 fp32)

  u16* w1b  = (u16*)(ws + off_W);
  u16* w2b  = (u16*)(ws + off_wt2);
  u16* wd1b = (u16*)(ws + off_wdt1);
  u16* wd2b = (u16*)(ws + off_wdt2);

  // --- weight prep (bf16, transposed to [N][K] / [t][N][K]) ---
  k_conv_w_t<<<dim3(20480), 256, 0, stream>>>(w_conv1, w1b, C1, INC, 5);
  k_conv_w_t<<<dim3(2560), 256, 0, stream>>>(w_conv2, w2b, C2, C1, 5);
  k_deconv_w_t<<<dim3(6144), 256, 0, stream>>>(w_dc1, wd1b, 3 * C2, DC1, 4);
  k_deconv_w_t<<<dim3(2048), 256, 0, stream>>>(w_dc2, wd2b, DC1, DC2, 4);
  k_prep_small<<<dim3(8), 256, 0, stream>>>(concept1, concept2, w_ca1, w_sim1, w_sim2,
                                            w_mlp, ws + off_qv);

  // --- conv1 + pool + bias -> t1 [80][100][512] fp32   (M=16000,N=512,K=10240)
  k_mfma_gemm<<<dim3(4, 125, 1), 256, 0, stream>>>(
      batch, w1b, ws + off_Y, b_conv1, 16000, 512, 10240, 200, 2048, 2, 0, 0, EP_POOL);

  // --- conv2 + pool + bias -> t2 [80][50][256] fp32    (M=8000,N=256,K=2560)
  k_mfma_gemm<<<dim3(2, 63, 1), 256, 0, stream>>>(
      ws + off_Y, w2b, ws + off_t2, b_conv2, 8000, 256, 2560, 100, 512, 2, 0, 0, EP_POOL);

  // --- kproj = t2 @ w_ca2^T : [4000][256] fp32
  k_gemm_nt<<<dim3(2, 63, 1), 256, 0, stream>>>(ws + off_t2, w_ca2, ws + off_kproj,
                                                4000, 256, 256);

  // --- attention (2 concepts x 80 rows) -> r [2][80][256]
  k_attention<<<dim3(160), 256, 0, stream>>>(ws + off_kproj, ws + off_t2, ws + off_qv,
                                             w_ca3, seg_len, ws + off_r);

  // --- cat [4000][768] fp32 (into W region; w1b dead)
  k_build_cat<<<dim3(12000), 256, 0, stream>>>(ws + off_t2, ws + off_r, ws + off_W,
                                               4000 * 768);

  // --- deconv1 per-tap GEMMs -> D1tap [4][4000][512] fp32 (M=4000,N=512,K=768)
  k_mfma_gemm<<<dim3(4, 32, 4), 256, 0, stream>>>(
      ws + off_W, wd1b, ws + off_X, b_dc1, 4000, 512, 768, 4000, 768, 0,
      512LL * 768, 4000LL * 512, EP_PLAIN);
  k_combine1<<<dim3(16000), 256, 0, stream>>>(ws + off_X, b_dc1, ws + off_Y,
                                              BM * L2 * DC1);

  // --- deconv2 per-tap GEMMs -> D2tap [4][8000][256] fp32 (M=8000,N=256,K=512)
  k_mfma_gemm<<<dim3(2, 63, 4), 256, 0, stream>>>(
      ws + off_Y, wd2b, ws + off_X, b_dc2, 8000, 256, 512, 8000, 512, 0,
      256LL * 512, 8000LL * 256, EP_PLAIN);

  // --- combine + final dot + sigmoid -> out (sc1 | sc2), fp32
  k_final<<<dim3(16000), 256, 0, stream>>>(ws + off_X, b_dc2, ws + off_qv, b_mlp, out);
}

// Round 4
// 908.185 us; speedup vs baseline: 12.4269x; 1.3513x over previous
//
#include <hip/hip_runtime.h>
#include <hip/hip_bf16.h>
#include <math.h>

// Problem constants
#define BB 4
#define MM 20
#define LL 200
#define INC 2048
#define C1 512
#define C2 256
#define CDIM 300
#define DC1 512
#define DC2 256
#define SDIM 1024
#define BM 80           // B*M
#define L2 100          // L/2
#define L4 50           // L/4

typedef unsigned short u16;
typedef __attribute__((ext_vector_type(8))) short bf16x8;
typedef __attribute__((ext_vector_type(4))) float f32x4;

__device__ __forceinline__ u16 f2bf_rne(float f) {
  unsigned u = __float_as_uint(f);
  unsigned r = u + 0x7FFFu + ((u >> 16) & 1u);
  return (u16)(r >> 16);
}
__device__ __forceinline__ float bf2f(u16 v) {
  return __uint_as_float(((unsigned)v) << 16);
}

// ---------------- generic fp32 -> bf16 cast (n8 = n/8, n % 8 == 0) ----------------
__global__ void k_cast_bf16(const float* __restrict__ in, u16* __restrict__ out, int n8) {
  int idx = blockIdx.x * 256 + threadIdx.x;
  if (idx >= n8) return;
  const float4* p = (const float4*)in + (long long)idx * 2;
  float4 a = p[0], b = p[1];
  uint4 o;
  o.x = (unsigned)f2bf_rne(a.x) | ((unsigned)f2bf_rne(a.y) << 16);
  o.y = (unsigned)f2bf_rne(a.z) | ((unsigned)f2bf_rne(a.w) << 16);
  o.z = (unsigned)f2bf_rne(b.x) | ((unsigned)f2bf_rne(b.y) << 16);
  o.w = (unsigned)f2bf_rne(b.z) | ((unsigned)f2bf_rne(b.w) << 16);
  *(uint4*)(out + (long long)idx * 8) = o;
}

// ---------------- weight transposes (emit bf16) ----------------
// conv weight [co][ci][t] -> [co][t][ci]  (= B[N][K], K = 5*Cin)
__global__ void k_conv_w_t(const float* __restrict__ in, u16* __restrict__ out,
                           int Cout, int Cin, int Kk) {
  int idx = blockIdx.x * 256 + threadIdx.x;
  int total = Cout * Cin * Kk;
  if (idx >= total) return;
  int ci = idx % Cin;
  int t  = (idx / Cin) % Kk;
  int co = idx / (Cin * Kk);
  out[idx] = f2bf_rne(in[(co * Cin + ci) * Kk + t]);
}

// deconv weight [ci][co][t] -> [t][co][ci]
__global__ void k_deconv_w_t(const float* __restrict__ in, u16* __restrict__ out,
                             int Cin, int Cout, int Kk) {
  int idx = blockIdx.x * 256 + threadIdx.x;
  int total = Cin * Cout * Kk;
  if (idx >= total) return;
  int ci = idx % Cin;
  int co = (idx / Cin) % Cout;
  int t  = idx / (Cin * Cout);
  out[idx] = f2bf_rne(in[(ci * Cout + co) * Kk + t]);
}

// ---------------- small precompute: q[z][b][c], v[z][b][c] ----------------
__global__ __launch_bounds__(256) void k_prep_small(
    const float* __restrict__ concept1, const float* __restrict__ concept2,
    const float* __restrict__ w_ca1, const float* __restrict__ w_sim1,
    const float* __restrict__ w_sim2, const float* __restrict__ w_mlp,
    float* __restrict__ qv) {
  int cz = blockIdx.x >> 2;
  int b  = blockIdx.x & 3;
  const float* con = cz ? concept2 : concept1;
  __shared__ float cvec[CDIM];
  __shared__ float chat[SDIM];
  int tid = threadIdx.x;
  for (int j = tid; j < CDIM; j += 256) cvec[j] = con[b * CDIM + j];
  __syncthreads();
  float accq = 0.f;
  for (int j = 0; j < CDIM; ++j) accq += cvec[j] * w_ca1[tid * CDIM + j];
  qv[(cz * 4 + b) * 256 + tid] = accq;
  for (int i = 0; i < 4; ++i) {
    int s = tid + i * 256;
    float a2 = 0.f;
    for (int j = 0; j < CDIM; ++j) a2 += cvec[j] * w_sim2[s * CDIM + j];
    chat[s] = a2 * w_mlp[s];
  }
  __syncthreads();
  float v = 0.f;
  for (int s = 0; s < SDIM; ++s) v += w_sim1[s * 256 + tid] * chat[s];
  qv[2048 + (cz * 4 + b) * 256 + tid] = v;
}

// ---------------- unified bf16-MFMA NT GEMM ----------------
// C[z][M][N] = A[M][K] * B[z][N][K]^T, A and B bf16. A row r -> (n=r/lr, l=r%lr);
// k = tap*cin+ci reads A[(n*lr + l+tap-pad)*cin + ci], zero outside (im2col conv).
// Plain GEMM: lr=M, cin=K, pad=0.
// Block swizzle: id = (y&7) + 8*(x + gx*(y>>3)) so the gx col-blocks of one
// row-stripe share (id mod 8) -> same XCD -> A stripe served from that L2.
// EP_PLAIN: fp32 store. EP_POOL: maxpool2(l)+bias -> bf16 store [n][lr/2][N].
#define EP_PLAIN 0
#define EP_POOL  1
#define LDK 72   // padded LDS row stride in u16 (144 B -> 4-bank rotation)

template <int EP>
__global__ __launch_bounds__(256) void k_mfma_gemm(
    const u16* __restrict__ A, const u16* __restrict__ Bw,
    void* __restrict__ C, const float* __restrict__ bias,
    int M, int N, int K, int lr, int cin, int pad, int gx, int gy,
    long long sB, long long sC) {
  __shared__ __align__(16) u16 As[128 * LDK];
  __shared__ __align__(16) u16 Bs[128 * LDK];
  int id = blockIdx.x;
  int x = (id >> 3) % gx;
  int y = (id & 7) + 8 * ((id >> 3) / gx);
  if (y >= gy) return;
  int row0 = y * 128, col0 = x * 128;
  int tid = threadIdx.x;
  int w = tid >> 6, ln = tid & 63;
  const u16* Bz = Bw + (long long)blockIdx.z * sB;

  // staging map: thread covers rows i*32 + (tid>>3), cols (tid&7)*8, i = 0..3
  int sub = (tid & 7) * 8;
  int rrb = tid >> 3;
  int an[4], al[4];
  #pragma unroll
  for (int i = 0; i < 4; ++i) {
    int r = row0 + i * 32 + rrb;
    if (r > M - 1) r = M - 1;
    an[i] = r / lr;
    al[i] = r - an[i] * lr;
  }
  f32x4 acc[4][4];
  #pragma unroll
  for (int i = 0; i < 4; ++i)
    #pragma unroll
    for (int j = 0; j < 4; ++j) acc[i][j] = (f32x4){0.f, 0.f, 0.f, 0.f};

  int wr = (w >> 1) * 64, wc = (w & 1) * 64;

  int tap = 0, ci0 = 0;
  for (int kc = 0; kc < K; kc += 64) {
    #pragma unroll
    for (int i = 0; i < 4; ++i) {
      int j = al[i] + tap - pad;
      uint4 pk = make_uint4(0u, 0u, 0u, 0u);
      if (j >= 0 && j < lr)
        pk = *(const uint4*)&A[(long long)(an[i] * lr + j) * cin + ci0 + sub];
      *(uint4*)&As[(i * 32 + rrb) * LDK + sub] = pk;
    }
    #pragma unroll
    for (int i = 0; i < 4; ++i) {
      int nr = col0 + i * 32 + rrb;
      *(uint4*)&Bs[(i * 32 + rrb) * LDK + sub] =
          *(const uint4*)&Bz[(long long)nr * K + kc + sub];
    }
    __syncthreads();
    #pragma unroll
    for (int ks = 0; ks < 2; ++ks) {
      bf16x8 af[4], bf[4];
      int koff = ks * 32 + (ln >> 4) * 8;
      int arow = wr + (ln & 15);
      int brow = wc + (ln & 15);
      #pragma unroll
      for (int mi = 0; mi < 4; ++mi)
        af[mi] = *(const bf16x8*)&As[(arow + mi * 16) * LDK + koff];
      #pragma unroll
      for (int ni = 0; ni < 4; ++ni)
        bf[ni] = *(const bf16x8*)&Bs[(brow + ni * 16) * LDK + koff];
      #pragma unroll
      for (int mi = 0; mi < 4; ++mi)
        #pragma unroll
        for (int ni = 0; ni < 4; ++ni)
          acc[mi][ni] = __builtin_amdgcn_mfma_f32_16x16x32_bf16(
              af[mi], bf[ni], acc[mi][ni], 0, 0, 0);
    }
    __syncthreads();
    ci0 += 64;
    if (ci0 >= cin) { ci0 = 0; ++tap; }
  }

  // epilogue: C/D layout col = lane&15, row = (lane>>4)*4 + reg
  if (EP == EP_PLAIN) {
    float* Cz = (float*)C + (long long)blockIdx.z * sC;
    #pragma unroll
    for (int mi = 0; mi < 4; ++mi) {
      int gbase = row0 + wr + mi * 16 + (ln >> 4) * 4;
      #pragma unroll
      for (int r = 0; r < 4; ++r) {
        int grow = gbase + r;
        if (grow < M) {
          #pragma unroll
          for (int ni = 0; ni < 4; ++ni) {
            int col = col0 + wc + ni * 16 + (ln & 15);
            Cz[(long long)grow * N + col] = acc[mi][ni][r];
          }
        }
      }
    }
  } else {
    u16* Cz = (u16*)C;
    #pragma unroll
    for (int mi = 0; mi < 4; ++mi) {
      int gbase = row0 + wr + mi * 16 + (ln >> 4) * 4;
      #pragma unroll
      for (int p = 0; p < 2; ++p) {
        int grow = gbase + 2 * p;
        if (grow < M) {
          int lo = grow >> 1;
          #pragma unroll
          for (int ni = 0; ni < 4; ++ni) {
            int col = col0 + wc + ni * 16 + (ln & 15);
            float v = fmaxf(acc[mi][ni][2 * p], acc[mi][ni][2 * p + 1]) + bias[col];
            Cz[(long long)lo * N + col] = f2bf_rne(v);
          }
        }
      }
    }
  }
}

// ---------------- attention: wave-parallel scores + softmax + weighted sum ----------------
__global__ __launch_bounds__(256) void k_attention(
    const float* __restrict__ kproj, const u16* __restrict__ t2b,
    const float* __restrict__ qv, const float* __restrict__ w_ca3,
    const int* __restrict__ seg_len, float* __restrict__ r_out) {
  int bm = blockIdx.x % BM;
  int cz = blockIdx.x / BM;
  int b = bm / MM;
  int tid = threadIdx.x, w = tid >> 6, ln = tid & 63;
  __shared__ float sq[256], sw[256], sa[L4 + 14];
  sq[tid] = qv[(cz * 4 + b) * 256 + tid];
  sw[tid] = w_ca3[tid];
  __syncthreads();
  int kmax = (seg_len[bm] + 3) >> 2;
  for (int k = w; k < L4; k += 4) {
    float val = 0.f;
    #pragma unroll
    for (int i = 0; i < 4; ++i) {
      int c = ln + 64 * i;
      val += tanhf(sq[c] + kproj[(bm * L4 + k) * 256 + c]) * sw[c];
    }
    for (int off = 32; off > 0; off >>= 1) val += __shfl_down(val, off, 64);
    if (ln == 0) sa[k] = (k < kmax) ? val : -1e15f;
  }
  __syncthreads();
  if (w == 0) {
    float sv = (ln < L4) ? sa[ln] : -3e38f;
    float mx = sv;
    for (int off = 32; off > 0; off >>= 1) mx = fmaxf(mx, __shfl_down(mx, off, 64));
    mx = __shfl(mx, 0, 64);
    float e = (ln < L4) ? expf(sv - mx) : 0.f;
    float s = e;
    for (int off = 32; off > 0; off >>= 1) s += __shfl_down(s, off, 64);
    s = __shfl(s, 0, 64);
    if (ln < L4) sa[ln] = e / s;
  }
  __syncthreads();
  float r = 0.f;
  for (int k = 0; k < L4; ++k) r += sa[k] * bf2f(t2b[(bm * L4 + k) * 256 + tid]);
  r_out[(cz * BM + bm) * 256 + tid] = r;
}

// ---------------- build cat matrix [4000][768] bf16 ----------------
__global__ void k_build_cat(const u16* __restrict__ t2b, const float* __restrict__ r_out,
                            u16* __restrict__ catm, int total) {
  int idx = blockIdx.x * 256 + threadIdx.x;
  if (idx >= total) return;
  int ci = idx % 768;
  int row = idx / 768;        // bm*50 + li
  int bm = row / L4;
  u16 v;
  if (ci < 256)      v = t2b[row * 256 + ci];
  else if (ci < 512) v = f2bf_rne(r_out[bm * 256 + (ci - 256)]);
  else               v = f2bf_rne(r_out[(BM + bm) * 256 + (ci - 512)]);
  catm[idx] = v;
}

// ---------------- deconv1 combine (2 taps + bias) -> d1 [80][100][512] bf16 ----------------
__global__ void k_combine1(const float* __restrict__ D1tap, const float* __restrict__ b_dc1,
                           u16* __restrict__ d1, int total) {
  int idx = blockIdx.x * 256 + threadIdx.x;
  if (idx >= total) return;
  int co = idx & 511;
  int lo = (idx >> 9) % L2;
  int n = idx / (512 * L2);
  int liA, tA, liB, tB;
  if (lo & 1) { tA = 2; liA = (lo - 1) >> 1; tB = 0; liB = (lo + 1) >> 1; }
  else        { tA = 3; liA = (lo >> 1) - 1; tB = 1; liB = lo >> 1; }
  float v = b_dc1[co];
  if (liA >= 0 && liA < L4) v += D1tap[((long long)tA * 4000 + n * L4 + liA) * 512 + co];
  if (liB >= 0 && liB < L4) v += D1tap[((long long)tB * 4000 + n * L4 + liB) * 512 + co];
  d1[idx] = f2bf_rne(v);
}

// ---------------- deconv2 combine + final projection + sigmoid ----------------
__global__ __launch_bounds__(256) void k_final(
    const float* __restrict__ D2tap, const float* __restrict__ b_dc2,
    const float* __restrict__ qv, const float* __restrict__ b_mlp,
    float* __restrict__ out) {
  int blk = blockIdx.x;          // n*200 + lo
  int n = blk / LL, lo = blk % LL;
  int b = n / MM, m = n % MM;
  int tid = threadIdx.x;
  int liA, tA, liB, tB;
  if (lo & 1) { tA = 2; liA = (lo - 1) >> 1; tB = 0; liB = (lo + 1) >> 1; }
  else        { tA = 3; liA = (lo >> 1) - 1; tB = 1; liB = lo >> 1; }
  float v = b_dc2[tid];
  if (liA >= 0 && liA < L2) v += D2tap[((long long)tA * 8000 + n * L2 + liA) * 256 + tid];
  if (liB >= 0 && liB < L2) v += D2tap[((long long)tB * 8000 + n * L2 + liB) * 256 + tid];
  float p1 = v * qv[2048 + (0 * 4 + b) * 256 + tid];
  float p2 = v * qv[2048 + (1 * 4 + b) * 256 + tid];
  for (int off = 32; off > 0; off >>= 1) {
    p1 += __shfl_down(p1, off, 64);
    p2 += __shfl_down(p2, off, 64);
  }
  __shared__ float s1[4], s2[4];
  if ((tid & 63) == 0) { s1[tid >> 6] = p1; s2[tid >> 6] = p2; }
  __syncthreads();
  if (tid == 0) {
    float bmlp = b_mlp[0];
    float a1 = s1[0] + s1[1] + s1[2] + s1[3] + bmlp;
    float a2 = s2[0] + s2[1] + s2[2] + s2[3] + bmlp;
    int t_idx = m * LL + lo;
    out[b * 4000 + t_idx]         = 1.f / (1.f + expf(-a1));
    out[16000 + b * 4000 + t_idx] = 1.f / (1.f + expf(-a2));
  }
}

// ---------------- host ----------------
extern "C" void kernel_launch(void* const* d_in, const int* in_sizes, int n_in,
                              void* d_out, int out_size, void* d_ws, size_t ws_size,
                              hipStream_t stream) {
  const float* batch    = (const float*)d_in[0];
  const int*   seg_len  = (const int*)d_in[1];
  const float* concept1 = (const float*)d_in[2];
  const float* concept2 = (const float*)d_in[3];
  const float* w_conv1  = (const float*)d_in[4];
  const float* b_conv1  = (const float*)d_in[5];
  const float* w_conv2  = (const float*)d_in[6];
  const float* b_conv2  = (const float*)d_in[7];
  const float* w_ca1    = (const float*)d_in[8];
  const float* w_ca2    = (const float*)d_in[9];
  const float* w_ca3    = (const float*)d_in[10];
  const float* w_dc1    = (const float*)d_in[11];
  const float* b_dc1    = (const float*)d_in[12];
  const float* w_dc2    = (const float*)d_in[13];
  const float* b_dc2    = (const float*)d_in[14];
  const float* w_sim1   = (const float*)d_in[15];
  const float* w_sim2   = (const float*)d_in[16];
  const float* w_mlp    = (const float*)d_in[17];
  const float* b_mlp    = (const float*)d_in[18];
  float* out = (float*)d_out;

  float* ws = (float*)d_ws;
  // workspace layout (float units) — total 26,091,520 f = 104.4 MB
  const long long off_qv    = 0;          //     4,096
  const long long off_r     = 4096;       //    40,960
  const long long off_kproj = 45056;      // 1,024,000 fp32
  const long long off_t1    = 1069056;    // 2,048,000 (t1 bf16: 4.096M u16)
  const long long off_t2    = 3117056;    //   512,000 (t2 bf16: 1.024M u16)
  const long long off_w2b   = 3629056;    //   327,680 (u16 ×2)
  const long long off_wd1b  = 3956736;    //   786,432
  const long long off_wd2b  = 4743168;    //   262,144
  const long long off_wca2b = 5005312;    //    32,768
  const long long off_w1b   = 5038080;    // 2,621,440
  const long long off_d1    = 7659520;    // 2,048,000 (d1 bf16)
  const long long off_BIG   = 9707520;    // 16,384,000 (batchb -> catm+D1tap -> D2tap)

  u16* batchb = (u16*)(ws + off_BIG);
  u16* catm   = (u16*)(ws + off_BIG);                 // after conv1, batchb dead
  float* D1tap = ws + off_BIG + 1536000;              // 8,192,000 f
  float* D2tap = ws + off_BIG + 1536000;              // overwrites D1tap after combine1
  u16* t1b  = (u16*)(ws + off_t1);
  u16* t2b  = (u16*)(ws + off_t2);
  u16* d1b  = (u16*)(ws + off_d1);
  u16* w1b  = (u16*)(ws + off_w1b);
  u16* w2b  = (u16*)(ws + off_w2b);
  u16* wd1b = (u16*)(ws + off_wd1b);
  u16* wd2b = (u16*)(ws + off_wd2b);
  u16* wca2b = (u16*)(ws + off_wca2b);

  // --- input/weight prep (bf16) ---
  k_cast_bf16<<<dim3(16000), 256, 0, stream>>>(batch, batchb, 4096000);
  k_cast_bf16<<<dim3(32), 256, 0, stream>>>(w_ca2, wca2b, 8192);
  k_conv_w_t<<<dim3(20480), 256, 0, stream>>>(w_conv1, w1b, C1, INC, 5);
  k_conv_w_t<<<dim3(2560), 256, 0, stream>>>(w_conv2, w2b, C2, C1, 5);
  k_deconv_w_t<<<dim3(6144), 256, 0, stream>>>(w_dc1, wd1b, 3 * C2, DC1, 4);
  k_deconv_w_t<<<dim3(2048), 256, 0, stream>>>(w_dc2, wd2b, DC1, DC2, 4);
  k_prep_small<<<dim3(8), 256, 0, stream>>>(concept1, concept2, w_ca1, w_sim1, w_sim2,
                                            w_mlp, ws + off_qv);

  // --- conv1 + pool + bias -> t1 bf16 [80][100][512]  (M=16000,N=512,K=10240)
  k_mfma_gemm<EP_POOL><<<dim3(512), 256, 0, stream>>>(
      batchb, w1b, t1b, b_conv1, 16000, 512, 10240, 200, 2048, 2, 4, 125, 0, 0);

  // --- conv2 + pool + bias -> t2 bf16 [80][50][256]   (M=8000,N=256,K=2560)
  k_mfma_gemm<EP_POOL><<<dim3(128), 256, 0, stream>>>(
      t1b, w2b, t2b, b_conv2, 8000, 256, 2560, 100, 512, 2, 2, 63, 0, 0);

  // --- kproj = t2 @ w_ca2^T : [4000][256] fp32  (M=4000,N=256,K=256)
  k_mfma_gemm<EP_PLAIN><<<dim3(64), 256, 0, stream>>>(
      t2b, wca2b, ws + off_kproj, nullptr, 4000, 256, 256, 4000, 256, 0, 2, 32, 0, 0);

  // --- attention (2 concepts x 80 rows) -> r [2][80][256] fp32
  k_attention<<<dim3(160), 256, 0, stream>>>(ws + off_kproj, t2b, ws + off_qv,
                                             w_ca3, seg_len, ws + off_r);

  // --- cat [4000][768] bf16 (into BIG; batchb dead)
  k_build_cat<<<dim3(12000), 256, 0, stream>>>(t2b, ws + off_r, catm, 4000 * 768);

  // --- deconv1 per-tap GEMMs -> D1tap [4][4000][512] fp32 (M=4000,N=512,K=768)
  k_mfma_gemm<EP_PLAIN><<<dim3(128, 1, 4), 256, 0, stream>>>(
      catm, wd1b, D1tap, nullptr, 4000, 512, 768, 4000, 768, 0, 4, 32,
      512LL * 768, 4000LL * 512);
  k_combine1<<<dim3(16000), 256, 0, stream>>>(D1tap, b_dc1, d1b, BM * L2 * DC1);

  // --- deconv2 per-tap GEMMs -> D2tap [4][8000][256] fp32 (M=8000,N=256,K=512)
  k_mfma_gemm<EP_PLAIN><<<dim3(128, 1, 4), 256, 0, stream>>>(
      d1b, wd2b, D2tap, nullptr, 8000, 256, 512, 8000, 512, 0, 2, 63,
      256LL * 512, 8000LL * 256);

  // --- combine + final dot + sigmoid -> out (sc1 | sc2), fp32
  k_final<<<dim3(16000), 256, 0, stream>>>(D2tap, b_dc2, ws + off_qv, b_mlp, out);
}